// Round 18
// baseline (9750.891 us; speedup 1.0000x reference)
//
#include <hip/hip_runtime.h>
#include <cstddef>

#define Bn 128   // batch
#define Nn 512   // n_node
#define Cc 4     // n_car
#define Tt 128   // decode steps
#define Dd 128   // model dim
#define Hh 8     // heads
#define NEGV -1e9f

// ---------------------------------------------------------------------------
// ONE kernel per (t,b); all intermediates in LDS/registers; OUTPUT = FLOAT32.
//  scores_h = node · (Wk1_h · q_h)      (reorder: no K1 materialization)
//  PV_h     = (p^T · node) · Wv_h       (reorder: no V materialization)
//  pointer  = node · (Wk2 · q2)         (reorder: no K2 materialization)
// ---------------------------------------------------------------------------
__global__ __launch_bounds__(512) void mono_kernel(
    const float* __restrict__ node,   // [B,N,D] f32
    const float* __restrict__ graph,  // [B,D] f32
    const float* __restrict__ sc,     // [T,B,C,129] f32
    const int* __restrict__ mask,     // [T,B,C,N] int32 bools
    const float* __restrict__ Wk1,    // [D,D]
    const float* __restrict__ Wv,     // [D,D]
    const float* __restrict__ Wk2,    // [D,D]
    const float* __restrict__ Wqf,    // [D,D]
    const float* __restrict__ Wout,   // [D,D]
    const float* __restrict__ Wqs,    // [129,D]
    float* __restrict__ out) {        // [T,B,2048] FLOAT32
  const int t = blockIdx.x, b = blockIdx.y, tid = threadIdx.x;
  const int c2 = tid >> 7, i = tid & 127;

  __shared__ float q[Cc][Dd];
  __shared__ float wq[Cc][Dd];
  __shared__ float p[Cc][Nn];
  __shared__ float pn[Cc][Dd];
  __shared__ float o[Cc][Dd];
  __shared__ float q2[Cc][Dd];
  __shared__ float redM[512];
  __shared__ float smax[Cc], ssum[Cc];
  __shared__ float gsh[2];
  __shared__ unsigned char mk[Cc][Nn];

  const float* nodeB = node + (size_t)b * (Nn * Dd);

  // ---- queries + mask staging
  {
    float acc = 0.f;
    for (int e = 0; e < Dd; ++e) acc += graph[b * Dd + e] * Wqf[e * Dd + i];
    const float* srow = &sc[(((size_t)t * Bn + b) * Cc + c2) * 129];
    for (int e = 0; e < 129; ++e) acc += srow[e] * Wqs[e * Dd + i];
    q[c2][i] = acc;
    o[c2][i] = 0.f;
  }
  for (int c = 0; c < Cc; ++c)
    mk[c][tid] =
        (mask[((size_t)t * Bn + b) * 2048 + (size_t)c * 512 + tid] != 0) ? 1
                                                                         : 0;
  __syncthreads();

  // ============ per-head attention ============
  for (int h = 0; h < Hh; ++h) {
    {
      const float* we = &Wk1[i * Dd + h * 16];
      float acc = 0.f;
#pragma unroll
      for (int j = 0; j < 16; ++j) acc += we[j] * q[c2][h * 16 + j];
      wq[c2][i] = acc;
    }
    __syncthreads();
    {
      const int n = tid;
      const float* nr = nodeB + (size_t)n * Dd;
      float s0 = 0.f, s1 = 0.f, s2 = 0.f, s3 = 0.f;
      for (int e = 0; e < Dd; ++e) {
        float x = nr[e];
        s0 += x * wq[0][e]; s1 += x * wq[1][e];
        s2 += x * wq[2][e]; s3 += x * wq[3][e];
      }
      p[0][n] = mk[0][n] ? NEGV : 0.25f * s0;
      p[1][n] = mk[1][n] ? NEGV : 0.25f * s1;
      p[2][n] = mk[2][n] ? NEGV : 0.25f * s2;
      p[3][n] = mk[3][n] ? NEGV : 0.25f * s3;
    }
    __syncthreads();
    {
      float m = -3.0e38f;
      for (int n = i; n < Nn; n += 128) m = fmaxf(m, p[c2][n]);
      redM[tid] = m;
    }
    __syncthreads();
    if (tid < Cc) {
      float mm = -3.0e38f;
      for (int z = 0; z < 128; ++z) mm = fmaxf(mm, redM[tid * 128 + z]);
      smax[tid] = mm;
    }
    __syncthreads();
    {
      float s = 0.f, m = smax[c2];
      for (int n = i; n < Nn; n += 128) {
        float e = __expf(p[c2][n] - m);
        p[c2][n] = e;
        s += e;
      }
      redM[tid] = s;
    }
    __syncthreads();
    if (tid < Cc) {
      float s = 0.f;
      for (int z = 0; z < 128; ++z) s += redM[tid * 128 + z];
      ssum[tid] = s;
    }
    __syncthreads();
    {
      float acc = 0.f;
      for (int n = 0; n < Nn; ++n) acc += p[c2][n] * nodeB[(size_t)n * Dd + i];
      pn[c2][i] = acc / ssum[c2];
    }
    __syncthreads();
    if (i < 16) {
      float acc = 0.f;
      for (int e = 0; e < Dd; ++e) acc += pn[c2][e] * Wv[e * Dd + h * 16 + i];
      o[c2][h * 16 + i] = acc;
    }
    __syncthreads();
  }

  // ---- q2 = o @ Wout ; w2q = Wk2 · q2
  {
    float acc = 0.f;
    for (int d = 0; d < Dd; ++d) acc += o[c2][d] * Wout[d * Dd + i];
    q2[c2][i] = acc;
  }
  __syncthreads();
  {
    const float* wr = &Wk2[i * Dd];
    float acc = 0.f;
    for (int e = 0; e < Dd; ++e) acc += wr[e] * q2[c2][e];
    wq[c2][i] = acc;
  }
  __syncthreads();

  // ---- pointer logits + LSE
  const int n = tid;
  float a[4] = {0.f, 0.f, 0.f, 0.f};
  {
    const float* nr = nodeB + (size_t)n * Dd;
    for (int e = 0; e < Dd; ++e) {
      float x = nr[e];
      a[0] += x * wq[0][e]; a[1] += x * wq[1][e];
      a[2] += x * wq[2][e]; a[3] += x * wq[3][e];
    }
  }
  const float rsq = 0.08838834764831845f;  // 1/sqrt(128)
  float lg[4];
  int mkb[4];
#pragma unroll
  for (int c = 0; c < 4; ++c) {
    mkb[c] = mk[c][n];
    float x = 10.0f * tanhf(a[c] * rsq);
    lg[c] = mkb[c] ? NEGV : x;
  }
  float m4 = fmaxf(fmaxf(lg[0], lg[1]), fmaxf(lg[2], lg[3]));
  redM[tid] = m4;
  __syncthreads();
  if (tid == 0) {
    float g = -3.0e38f;
    for (int z = 0; z < 512; ++z) g = fmaxf(g, redM[z]);
    gsh[0] = g;
  }
  __syncthreads();
  float gm = gsh[0];
  float se = __expf(lg[0] - gm) + __expf(lg[1] - gm) +
             __expf(lg[2] - gm) + __expf(lg[3] - gm);
  redM[tid] = se;
  __syncthreads();
  if (tid == 0) {
    float s = 0.f;
    for (int z = 0; z < 512; ++z) s += redM[z];
    gsh[1] = s;
  }
  __syncthreads();
  float sub = gm + logf(gsh[1]);
  // ---- FLOAT32 output
#pragma unroll
  for (int c = 0; c < 4; ++c) {
    float v;
    if (mkb[c]) {
      v = NEGV - sub;                       // matches ref formula exactly
      v = fminf(fmaxf(v, -1.0001e9f), -9.99e8f);  // bound anomalies
    } else {
      v = lg[c] - sub;                      // true range [-27.7, 0]
      v = fminf(fmaxf(v, -45.0f), 0.0f);    // bound anomalies/NaN
    }
    out[((size_t)t * Bn + b) * 2048 + c * 512 + n] = v;
  }
}

// ---------------------------------------------------------------------------
extern "C" void kernel_launch(void* const* d_in, const int* in_sizes, int n_in,
                              void* d_out, int out_size, void* d_ws,
                              size_t ws_size, hipStream_t stream) {
  // dict order; floats FP32, mask INT32 bools, OUTPUT FLOAT32.
  const float* node = (const float*)d_in[0];
  const float* graph = (const float*)d_in[1];
  const float* sc = (const float*)d_in[2];
  const int* mask = (const int*)d_in[3];
  const float* Wk1 = (const float*)d_in[4];
  const float* Wv = (const float*)d_in[5];
  const float* Wk2 = (const float*)d_in[6];
  const float* Wqf = (const float*)d_in[7];
  const float* Wout = (const float*)d_in[8];
  const float* Wqs = (const float*)d_in[9];
  float* out = (float*)d_out;

  hipLaunchKernelGGL(mono_kernel, dim3(Tt, Bn), dim3(512), 0, stream,
                     node, graph, sc, mask, Wk1, Wv, Wk2, Wqf, Wout, Wqs, out);
}

// Round 19
// 2131.668 us; speedup vs baseline: 4.5743x; 4.5743x over previous
//
#include <hip/hip_runtime.h>
#include <cstddef>

#define Bn 128   // batch
#define Nn 512   // n_node
#define Cc 4     // n_car
#define Tt 128   // decode steps
#define Dd 128   // model dim
#define Hh 8     // heads
#define DH 16    // per-head dim
#define NEGV -1e9f

#define TQ 16    // t-tile in MHA kernel
#define TT 8     // t-tile in pointer kernel

// ---------------------------------------------------------------------------
// Kernel 1: Qf = graph @ Wq_fixed  [B,D] f32 -> ws.
// ---------------------------------------------------------------------------
__global__ __launch_bounds__(128) void qfixed_kernel(
    const float* __restrict__ g, const float* __restrict__ Wq,
    float* __restrict__ Qf) {
  int b = blockIdx.x, d = threadIdx.x;
  __shared__ float row[Dd];
  row[d] = g[b * Dd + d];
  __syncthreads();
  float acc = 0.f;
  for (int e = 0; e < Dd; ++e) acc += row[e] * Wq[e * Dd + d];
  Qf[b * Dd + d] = acc;
}

// ---------------------------------------------------------------------------
// Kernel 2: K1/V/K2 = node @ {Wk1,Wv,Wk2} f32 -> ws.
// ---------------------------------------------------------------------------
#define PROWS 32
__global__ __launch_bounds__(128) void proj3_kernel(
    const float* __restrict__ X,
    const float* __restrict__ W1, const float* __restrict__ W2,
    const float* __restrict__ W3,
    float* __restrict__ O1, float* __restrict__ O2, float* __restrict__ O3) {
  int r0 = blockIdx.x * PROWS, d = threadIdx.x;
  __shared__ __align__(16) float rows[PROWS][Dd];
  for (int r = 0; r < PROWS; ++r)
    rows[r][d] = X[(size_t)(r0 + r) * Dd + d];
  __syncthreads();

  const float* Ws[3] = {W1, W2, W3};
  float* Os[3] = {O1, O2, O3};
  for (int m = 0; m < 3; ++m) {
    const float* __restrict__ W = Ws[m];
    float acc[PROWS];
#pragma unroll
    for (int r = 0; r < PROWS; ++r) acc[r] = 0.f;
    for (int e4 = 0; e4 < Dd / 4; ++e4) {
      float w0 = W[(e4 * 4 + 0) * Dd + d];
      float w1 = W[(e4 * 4 + 1) * Dd + d];
      float w2 = W[(e4 * 4 + 2) * Dd + d];
      float w3 = W[(e4 * 4 + 3) * Dd + d];
#pragma unroll
      for (int r = 0; r < PROWS; ++r) {
        float4 x = *(const float4*)&rows[r][e4 * 4];
        acc[r] += x.x * w0 + x.y * w1 + x.z * w2 + x.w * w3;
      }
    }
    float* __restrict__ O = Os[m];
    for (int r = 0; r < PROWS; ++r) O[(size_t)(r0 + r) * Dd + d] = acc[r];
  }
}

// ---------------------------------------------------------------------------
// Kernel 3: fused Q_step + MHA + @Wout -> q2 (f32, d_out scratch slots
// out[t,b, c*512+0..127]).  grid (T/TQ, C, B), 512 threads.
// ---------------------------------------------------------------------------
__global__ __launch_bounds__(512) void mha_kernel(
    const float* __restrict__ Qf,        // [B,D] f32 ws
    const float* __restrict__ sc,        // [T,B,C,129] f32
    const int* __restrict__ mask,        // [T,B,C,N] int32 bools
    const float* __restrict__ K1,        // [B,N,D] f32 ws
    const float* __restrict__ V,         // [B,N,D] f32 ws
    const float* __restrict__ Wqs,       // [129,D] f32
    const float* __restrict__ Wout,      // [D,D] f32
    float* __restrict__ outw) {          // d_out: q2 scratch
  int t0 = blockIdx.x * TQ;
  int c = blockIdx.y;
  int b = blockIdx.z;
  int tid = threadIdx.x;

  __shared__ __align__(16) float qtile[TQ * Dd];
  __shared__ __align__(16) float otile[TQ * Dd];
  __shared__ __align__(16) float region[16384];  // scores[0..8191] | vtile[8192..]

  // ---- mask bits for this thread's n across TQ t-steps (int32 reads)
  int n = tid;
  unsigned int mbits = 0;
  for (int tq = 0; tq < TQ; ++tq) {
    int mv = mask[(size_t)(t0 + tq) * (Bn * Cc * Nn) +
                  ((size_t)b * Cc + c) * Nn + n];
    mbits |= ((unsigned)(mv != 0)) << tq;
  }

  // ---- phase 1: q = Qf[b] + sc @ Wqs
  for (int i = tid; i < TQ * 129; i += 512) {
    int tq = i / 129, e = i % 129;
    region[i] = sc[(((size_t)(t0 + tq) * Bn + b) * Cc + c) * 129 + e];
  }
  __syncthreads();
  for (int i = tid; i < TQ * Dd; i += 512) {
    int tq = i >> 7, d = i & 127;
    float acc = Qf[b * Dd + d];
    for (int e = 0; e < 129; ++e)
      acc += region[tq * 129 + e] * Wqs[e * Dd + d];
    qtile[i] = acc;
  }
  __syncthreads();

  // ---- per-head attention
  for (int h = 0; h < Hh; ++h) {
    // stage V head-slice: region[8192 + nn*16 + j]
    for (int i = tid; i < Nn * 4; i += 512) {
      int nn = i >> 2, j = i & 3;
      float4 v4 = *(const float4*)&V[((size_t)b * Nn + nn) * Dd + h * DH + j * 4];
      *(float4*)&region[8192 + nn * 16 + j * 4] = v4;
    }
    // scores: thread = n
    {
      const float* k1p = &K1[((size_t)b * Nn + n) * Dd + h * DH];
      float4 ka = *(const float4*)(k1p + 0);
      float4 kb = *(const float4*)(k1p + 4);
      float4 kc = *(const float4*)(k1p + 8);
      float4 kd = *(const float4*)(k1p + 12);
      for (int tq = 0; tq < TQ; ++tq) {
        const float4* q4 = (const float4*)&qtile[tq * Dd + h * DH];
        float4 qa = q4[0], qb = q4[1], qc = q4[2], qd = q4[3];
        float s = ka.x * qa.x + ka.y * qa.y + ka.z * qa.z + ka.w * qa.w +
                  kb.x * qb.x + kb.y * qb.y + kb.z * qb.z + kb.w * qb.w +
                  kc.x * qc.x + kc.y * qc.y + kc.z * qc.z + kc.w * qc.w +
                  kd.x * qd.x + kd.y * qd.y + kd.z * qd.z + kd.w * qd.w;
        s *= 0.25f;  // 1/sqrt(16)
        region[tq * Nn + n] = ((mbits >> tq) & 1) ? NEGV : s;
      }
    }
    __syncthreads();
    // softmax: 8 waves, wave w handles rows 2w, 2w+1
    {
      int w = tid >> 6, lane = tid & 63;
      for (int r = 0; r < 2; ++r) {
        int tq = w * 2 + r;
        float* row = &region[tq * Nn];
        float v[8];
        float lmax = -3.0e38f;
#pragma unroll
        for (int k = 0; k < 8; ++k) {
          v[k] = row[lane + 64 * k];
          lmax = fmaxf(lmax, v[k]);
        }
#pragma unroll
        for (int off = 32; off; off >>= 1)
          lmax = fmaxf(lmax, __shfl_xor(lmax, off, 64));
        float lsum = 0.f;
#pragma unroll
        for (int k = 0; k < 8; ++k) {
          v[k] = __expf(v[k] - lmax);
          lsum += v[k];
        }
#pragma unroll
        for (int off = 32; off; off >>= 1) lsum += __shfl_xor(lsum, off, 64);
        float inv = 1.0f / lsum;
#pragma unroll
        for (int k = 0; k < 8; ++k) row[lane + 64 * k] = v[k] * inv;
      }
    }
    __syncthreads();
    // stage C: attn @ V_head -> otile[tq][h*16+d]
    if (tid < 256) {
      int tq = tid >> 4, d = tid & 15;
      const float4* s4 = (const float4*)&region[tq * Nn];
      float acc = 0.f;
      for (int n4 = 0; n4 < Nn / 4; ++n4) {
        float4 p = s4[n4];
        int nb = n4 * 4;
        acc += p.x * region[8192 + (nb + 0) * 16 + d] +
               p.y * region[8192 + (nb + 1) * 16 + d] +
               p.z * region[8192 + (nb + 2) * 16 + d] +
               p.w * region[8192 + (nb + 3) * 16 + d];
      }
      otile[tq * Dd + h * DH + d] = acc;
    }
    __syncthreads();
  }

  // ---- stage D: q2 = otile @ Wout -> d_out scratch
  for (int i = tid; i < 16384; i += 512) region[i] = Wout[i];
  __syncthreads();
  for (int i = tid; i < TQ * Dd; i += 512) {
    int tq = i >> 7, e = i & 127;
    float acc = 0.f;
    for (int d4 = 0; d4 < Dd / 4; ++d4) {
      float4 o = *(const float4*)&otile[tq * Dd + d4 * 4];
      acc += o.x * region[(d4 * 4 + 0) * Dd + e] +
             o.y * region[(d4 * 4 + 1) * Dd + e] +
             o.z * region[(d4 * 4 + 2) * Dd + e] +
             o.w * region[(d4 * 4 + 3) * Dd + e];
    }
    outw[(((size_t)(t0 + tq) * Bn + b) * 2048) + c * 512 + e] = acc;
  }
}

// ---------------------------------------------------------------------------
// Kernel 4: pointer logits + log_softmax -> out [T,B,2048] f32.
// grid (T/TT, B), 512 threads. Reads q2 scratch rows, then overwrites them.
// ---------------------------------------------------------------------------
__global__ __launch_bounds__(512) void pointer_kernel(
    const float* __restrict__ K2,        // [B,N,D] f32 ws
    const int* __restrict__ mask,        // int32 bools
    float* __restrict__ outw) {          // [T,B,2048] f32 (+q2 scratch)
  int t0 = blockIdx.x * TT;
  int b = blockIdx.y;
  int tid = threadIdx.x;
  __shared__ __align__(16) float q2t[TT * Cc * Dd];  // 16 KB
  __shared__ __align__(16) float lg[TT * Cc * Nn];   // 64 KB

  // stage q2 scratch for rows t0..t0+TT-1 (read BEFORE overwriting)
  for (int i = tid; i < TT * Cc * Dd; i += 512) {
    int tt = i >> 9, rest = i & 511;
    int c = rest >> 7, d = rest & 127;
    q2t[i] = outw[((size_t)(t0 + tt) * Bn + b) * 2048 + c * 512 + d];
  }
  __syncthreads();

  int n = tid;
  const float* k2p = &K2[((size_t)b * Nn + n) * Dd];
  float acc[TT * Cc];
#pragma unroll
  for (int i = 0; i < TT * Cc; ++i) acc[i] = 0.f;
  for (int dc = 0; dc < 4; ++dc) {
    float4 k4[8];
#pragma unroll
    for (int j = 0; j < 8; ++j) k4[j] = *(const float4*)&k2p[dc * 32 + j * 4];
#pragma unroll
    for (int tc = 0; tc < TT * Cc; ++tc) {
      const float4* q4 = (const float4*)&q2t[tc * Dd + dc * 32];
      float s = 0.f;
#pragma unroll
      for (int j = 0; j < 8; ++j) {
        float4 q = q4[j];
        s += k4[j].x * q.x + k4[j].y * q.y + k4[j].z * q.z + k4[j].w * q.w;
      }
      acc[tc] += s;
    }
  }
  const float rsqD = 0.08838834764831845f;  // 1/sqrt(128)
  for (int tc = 0; tc < TT * Cc; ++tc) {
    int tt = tc >> 2, c = tc & 3;
    float lgt = 10.0f * tanhf(acc[tc] * rsqD);
    int mv = mask[(size_t)(t0 + tt) * (Bn * Cc * Nn) +
                  ((size_t)b * Cc + c) * Nn + n];
    lg[tt * 2048 + c * Nn + n] = mv ? NEGV : lgt;
  }
  __syncthreads();

  // log_softmax per tt row (2048 wide); wave w handles row w
  int w = tid >> 6, lane = tid & 63;
  float* row = &lg[w * 2048];
  float v[32];
  float lmax = -3.0e38f;
#pragma unroll
  for (int k = 0; k < 32; ++k) {
    v[k] = row[lane + 64 * k];
    lmax = fmaxf(lmax, v[k]);
  }
#pragma unroll
  for (int off = 32; off; off >>= 1)
    lmax = fmaxf(lmax, __shfl_xor(lmax, off, 64));
  float lsum = 0.f;
#pragma unroll
  for (int k = 0; k < 32; ++k) lsum += __expf(v[k] - lmax);
#pragma unroll
  for (int off = 32; off; off >>= 1) lsum += __shfl_xor(lsum, off, 64);
  float sub = lmax + logf(lsum);
  float* op = &outw[((size_t)(t0 + w) * Bn + b) * 2048];
#pragma unroll
  for (int k = 0; k < 32; ++k) op[lane + 64 * k] = v[k] - sub;
}

// ---------------------------------------------------------------------------
extern "C" void kernel_launch(void* const* d_in, const int* in_sizes, int n_in,
                              void* d_out, int out_size, void* d_ws,
                              size_t ws_size, hipStream_t stream) {
  // dict order; floats FP32, mask INT32 bools, OUTPUT FLOAT32.
  const float* node = (const float*)d_in[0];
  const float* graph = (const float*)d_in[1];
  const float* sc = (const float*)d_in[2];
  const int* mask = (const int*)d_in[3];
  const float* Wk1 = (const float*)d_in[4];
  const float* Wv = (const float*)d_in[5];
  const float* Wk2 = (const float*)d_in[6];
  const float* Wqf = (const float*)d_in[7];
  const float* Wout = (const float*)d_in[8];
  const float* Wqs = (const float*)d_in[9];
  float* out = (float*)d_out;

  // ws (97 MiB, within proven 113 MiB): Qf@0 | K1@1MiB | V@33MiB | K2@65MiB
  char* ws = (char*)d_ws;
  float* Qf = (float*)(ws);
  float* K1 = (float*)(ws + (1u << 20));
  float* V = (float*)(ws + (1u << 20) + (1u << 25));
  float* K2 = (float*)(ws + (1u << 20) + 2u * (1u << 25));

  hipLaunchKernelGGL(qfixed_kernel, dim3(Bn), dim3(128), 0, stream,
                     graph, Wqf, Qf);
  hipLaunchKernelGGL(proj3_kernel, dim3((Bn * Nn) / PROWS), dim3(128), 0,
                     stream, node, Wk1, Wv, Wk2, K1, V, K2);
  hipLaunchKernelGGL(mha_kernel, dim3(Tt / TQ, Cc, Bn), dim3(512), 0, stream,
                     Qf, sc, mask, K1, V, Wqs, Wout, out);
  hipLaunchKernelGGL(pointer_kernel, dim3(Tt / TT, Bn), dim3(512), 0, stream,
                     K2, mask, out);
}

// Round 20
// 1599.907 us; speedup vs baseline: 6.0947x; 1.3324x over previous
//
#include <hip/hip_runtime.h>
#include <cstddef>

#define Bn 128   // batch
#define Nn 512   // n_node
#define Cc 4     // n_car
#define Tt 128   // decode steps
#define Dd 128   // model dim
#define Hh 8     // heads
#define NEGV -1e9f

#define TQ 16    // t-tile in MHA kernel
#define TT 8     // t-tile in pointer kernel

typedef unsigned short u16;
typedef unsigned int u32;
typedef __attribute__((ext_vector_type(8))) short bf16x8;
typedef __attribute__((ext_vector_type(4))) float f32x4;

__device__ __forceinline__ u16 f2b(float f) {
  union { float f; u32 i; } x; x.f = f;
  u32 i = x.i; i += 0x7fffu + ((i >> 16) & 1u);
  return (u16)(i >> 16);
}

// ---------------------------------------------------------------------------
// Kernel 1: Qf = graph @ Wq_fixed  [B,D] f32 -> ws.
// ---------------------------------------------------------------------------
__global__ __launch_bounds__(128) void qfixed_kernel(
    const float* __restrict__ g, const float* __restrict__ Wq,
    float* __restrict__ Qf) {
  int b = blockIdx.x, d = threadIdx.x;
  __shared__ float row[Dd];
  row[d] = g[b * Dd + d];
  __syncthreads();
  float acc = 0.f;
  for (int e = 0; e < Dd; ++e) acc += row[e] * Wq[e * Dd + d];
  Qf[b * Dd + d] = acc;
}

// ---------------------------------------------------------------------------
// Kernel 2: K1b (bf16), V (f32), K2 (f32) projections -> ws.
// ---------------------------------------------------------------------------
#define PROWS 32
__global__ __launch_bounds__(128) void proj3_kernel(
    const float* __restrict__ X,
    const float* __restrict__ W1, const float* __restrict__ W2,
    const float* __restrict__ W3,
    u16* __restrict__ O1, float* __restrict__ O2, float* __restrict__ O3) {
  int r0 = blockIdx.x * PROWS, d = threadIdx.x;
  __shared__ __align__(16) float rows[PROWS][Dd];
  for (int r = 0; r < PROWS; ++r)
    rows[r][d] = X[(size_t)(r0 + r) * Dd + d];
  __syncthreads();

  {
    float acc[PROWS];
#pragma unroll
    for (int r = 0; r < PROWS; ++r) acc[r] = 0.f;
    for (int e4 = 0; e4 < Dd / 4; ++e4) {
      float w0 = W1[(e4 * 4 + 0) * Dd + d];
      float w1 = W1[(e4 * 4 + 1) * Dd + d];
      float w2 = W1[(e4 * 4 + 2) * Dd + d];
      float w3 = W1[(e4 * 4 + 3) * Dd + d];
#pragma unroll
      for (int r = 0; r < PROWS; ++r) {
        float4 x = *(const float4*)&rows[r][e4 * 4];
        acc[r] += x.x * w0 + x.y * w1 + x.z * w2 + x.w * w3;
      }
    }
    for (int r = 0; r < PROWS; ++r) O1[(size_t)(r0 + r) * Dd + d] = f2b(acc[r]);
  }
  {
    float acc[PROWS];
#pragma unroll
    for (int r = 0; r < PROWS; ++r) acc[r] = 0.f;
    for (int e4 = 0; e4 < Dd / 4; ++e4) {
      float w0 = W2[(e4 * 4 + 0) * Dd + d];
      float w1 = W2[(e4 * 4 + 1) * Dd + d];
      float w2 = W2[(e4 * 4 + 2) * Dd + d];
      float w3 = W2[(e4 * 4 + 3) * Dd + d];
#pragma unroll
      for (int r = 0; r < PROWS; ++r) {
        float4 x = *(const float4*)&rows[r][e4 * 4];
        acc[r] += x.x * w0 + x.y * w1 + x.z * w2 + x.w * w3;
      }
    }
    for (int r = 0; r < PROWS; ++r) O2[(size_t)(r0 + r) * Dd + d] = acc[r];
  }
  {
    float acc[PROWS];
#pragma unroll
    for (int r = 0; r < PROWS; ++r) acc[r] = 0.f;
    for (int e4 = 0; e4 < Dd / 4; ++e4) {
      float w0 = W3[(e4 * 4 + 0) * Dd + d];
      float w1 = W3[(e4 * 4 + 1) * Dd + d];
      float w2 = W3[(e4 * 4 + 2) * Dd + d];
      float w3 = W3[(e4 * 4 + 3) * Dd + d];
#pragma unroll
      for (int r = 0; r < PROWS; ++r) {
        float4 x = *(const float4*)&rows[r][e4 * 4];
        acc[r] += x.x * w0 + x.y * w1 + x.z * w2 + x.w * w3;
      }
    }
    for (int r = 0; r < PROWS; ++r) O3[(size_t)(r0 + r) * Dd + d] = acc[r];
  }
}

// ---------------------------------------------------------------------------
// Kernel 3: MFMA MHA. grid (T/TQ, C, B), 512 threads (8 waves).
// scores: mfma 16x16x32 bf16 (K=16 zero-padded); PV: mfma K=32, wave-split.
// ---------------------------------------------------------------------------
__global__ __launch_bounds__(512) void mha_kernel(
    const float* __restrict__ Qf,        // [B,D] f32 ws
    const float* __restrict__ sc,        // [T,B,C,129] f32
    const int* __restrict__ mask,        // [T,B,C,N] int32
    const u16* __restrict__ K1b,         // [B,N,D] bf16 ws
    const float* __restrict__ V,         // [B,N,D] f32 ws
    const float* __restrict__ Wqs,       // [129,D] f32
    const float* __restrict__ Wout,      // [D,D] f32
    float* __restrict__ outw) {          // d_out: q2 scratch
  const int t0 = blockIdx.x * TQ;
  const int c = blockIdx.y;
  const int b = blockIdx.z;
  const int tid = threadIdx.x;
  const int w = tid >> 6, lane = tid & 63;
  const int l15 = lane & 15, g = lane >> 4;

  __shared__ __align__(16) float qtile[TQ * 132];     // pad 132
  __shared__ __align__(16) float scores[TQ * 516];    // f32 scores / Pb bf16 / staging
  __shared__ __align__(16) u16 Vt[16 * 520];          // V-head transposed bf16
  __shared__ __align__(16) float otp[8 * 272];        // PV partials [w][16][17]
  __shared__ __align__(16) float otile[TQ * 128];
  __shared__ u32 mkbits[16 * 16];                     // [tq][n/32]

  u16* Pb = (u16*)scores;  // bf16 P, rows stride 520 (aliases scores region)

  // ---- phase 0: mask bitset
  {
    int n = tid;
    u32 mbits = 0;
    for (int tq = 0; tq < TQ; ++tq) {
      int mv = mask[(size_t)(t0 + tq) * (Bn * Cc * Nn) +
                    ((size_t)b * Cc + c) * Nn + n];
      mbits |= ((u32)(mv != 0)) << tq;
    }
    for (int tq = 0; tq < TQ; ++tq) {
      unsigned long long bal = __ballot((mbits >> tq) & 1u);
      if (lane == 0) {
        mkbits[tq * 16 + 2 * w] = (u32)bal;
        mkbits[tq * 16 + 2 * w + 1] = (u32)(bal >> 32);
      }
    }
  }

  // ---- phase 1: qtile = Qf + sc @ Wqs  (staging via scores region)
  for (int i = tid; i < TQ * 129; i += 512) {
    int tq = i / 129, e = i % 129;
    scores[i] = sc[(((size_t)(t0 + tq) * Bn + b) * Cc + c) * 129 + e];
  }
  __syncthreads();
  for (int i = tid; i < TQ * Dd; i += 512) {
    int tq = i >> 7, d = i & 127;
    float acc = Qf[b * Dd + d];
    for (int e = 0; e < 129; ++e)
      acc += scores[tq * 129 + e] * Wqs[e * Dd + d];
    qtile[tq * 132 + d] = acc;
  }
  __syncthreads();

  // ---- per-head loop
  for (int h = 0; h < Hh; ++h) {
    // (a) stage Vt (transposed bf16) + scores mfma
    for (int i = tid; i < 2048; i += 512) {
      int n = i >> 2, jj = i & 3;
      float4 v4 =
          *(const float4*)&V[((size_t)b * Nn + n) * Dd + h * 16 + jj * 4];
      int d0 = jj * 4;
      Vt[(d0 + 0) * 520 + n] = f2b(v4.x);
      Vt[(d0 + 1) * 520 + n] = f2b(v4.y);
      Vt[(d0 + 2) * 520 + n] = f2b(v4.z);
      Vt[(d0 + 3) * 520 + n] = f2b(v4.w);
    }
    {
      // A-frag: Q_h row m=l15, k=(g*8+j), zero for k>=16
      bf16x8 a8 = (bf16x8)(short)0;
      if (g < 2) {
        float4 qa = *(const float4*)&qtile[l15 * 132 + h * 16 + g * 8];
        float4 qb = *(const float4*)&qtile[l15 * 132 + h * 16 + g * 8 + 4];
        a8[0] = (short)f2b(qa.x); a8[1] = (short)f2b(qa.y);
        a8[2] = (short)f2b(qa.z); a8[3] = (short)f2b(qa.w);
        a8[4] = (short)f2b(qb.x); a8[5] = (short)f2b(qb.y);
        a8[6] = (short)f2b(qb.z); a8[7] = (short)f2b(qb.w);
      }
      for (int nt = w * 4; nt < w * 4 + 4; ++nt) {
        int n0 = nt * 16;
        bf16x8 b8 = (bf16x8)(short)0;
        if (g < 2) {
          const u16* kp =
              &K1b[((size_t)b * Nn + n0 + l15) * Dd + h * 16 + g * 8];
          uint4 kv = *(const uint4*)kp;
          union { uint4 u; bf16x8 s; } cv; cv.u = kv;
          b8 = cv.s;
        }
        f32x4 cc = {0.f, 0.f, 0.f, 0.f};
        cc = __builtin_amdgcn_mfma_f32_16x16x32_bf16(a8, b8, cc, 0, 0, 0);
#pragma unroll
        for (int r = 0; r < 4; ++r)
          scores[(g * 4 + r) * 516 + n0 + l15] = cc[r];
      }
    }
    __syncthreads();

    // (b) softmax: wave w rows {2w, 2w+1}; hold p in regs, then write Pb bf16
    float pv[16];
#pragma unroll
    for (int r = 0; r < 2; ++r) {
      int tq = 2 * w + r;
      float mx = -3.0e38f;
#pragma unroll
      for (int k = 0; k < 8; ++k) {
        int n = lane + 64 * k;
        float s = scores[tq * 516 + n];
        u32 bit = (mkbits[tq * 16 + (n >> 5)] >> (n & 31)) & 1u;
        s = bit ? NEGV : 0.25f * s;
        pv[r * 8 + k] = s;
        mx = fmaxf(mx, s);
      }
#pragma unroll
      for (int off = 32; off; off >>= 1)
        mx = fmaxf(mx, __shfl_xor(mx, off, 64));
      float sum = 0.f;
#pragma unroll
      for (int k = 0; k < 8; ++k) {
        float e = __expf(pv[r * 8 + k] - mx);
        pv[r * 8 + k] = e;
        sum += e;
      }
#pragma unroll
      for (int off = 32; off; off >>= 1) sum += __shfl_xor(sum, off, 64);
      float inv = 1.0f / sum;
#pragma unroll
      for (int k = 0; k < 8; ++k) pv[r * 8 + k] *= inv;
    }
    __syncthreads();  // all f32 score reads done
#pragma unroll
    for (int r = 0; r < 2; ++r) {
      int tq = 2 * w + r;
#pragma unroll
      for (int k = 0; k < 8; ++k)
        Pb[tq * 520 + lane + 64 * k] = f2b(pv[r * 8 + k]);
    }
    __syncthreads();  // Pb ready

    // (d) PV: wave w covers k in [64w, 64w+64): 2 mfma K=32
    {
      f32x4 cc = {0.f, 0.f, 0.f, 0.f};
#pragma unroll
      for (int kk = 0; kk < 2; ++kk) {
        int k0 = w * 64 + kk * 32;
        union { uint4 u; bf16x8 s; } pa, vb;
        pa.u = *(const uint4*)&Pb[l15 * 520 + k0 + g * 8];
        vb.u = *(const uint4*)&Vt[l15 * 520 + k0 + g * 8];
        cc = __builtin_amdgcn_mfma_f32_16x16x32_bf16(pa.s, vb.s, cc, 0, 0, 0);
      }
#pragma unroll
      for (int r = 0; r < 4; ++r)
        otp[w * 272 + (g * 4 + r) * 17 + l15] = cc[r];
    }
    __syncthreads();

    // (e) reduce partials -> otile[:, h*16..]
    if (tid < 256) {
      int tq = tid >> 4, d = tid & 15;
      float s = 0.f;
#pragma unroll
      for (int w2 = 0; w2 < 8; ++w2) s += otp[w2 * 272 + tq * 17 + d];
      otile[tq * 128 + h * 16 + d] = s;
    }
    __syncthreads();
  }

  // ---- Wout phase (fp32, two-half staging in scores region)
  float acc4[4] = {0.f, 0.f, 0.f, 0.f};
  for (int half = 0; half < 2; ++half) {
    __syncthreads();
    for (int i = tid; i < 8192; i += 512) scores[i] = Wout[half * 8192 + i];
    __syncthreads();
#pragma unroll
    for (int ii = 0; ii < 4; ++ii) {
      int i = tid + ii * 512;
      int tq = i >> 7, e = i & 127;
      float a = 0.f;
      for (int d4 = 0; d4 < 16; ++d4) {
        float4 o = *(const float4*)&otile[tq * 128 + half * 64 + d4 * 4];
        a += o.x * scores[(d4 * 4 + 0) * 128 + e] +
             o.y * scores[(d4 * 4 + 1) * 128 + e] +
             o.z * scores[(d4 * 4 + 2) * 128 + e] +
             o.w * scores[(d4 * 4 + 3) * 128 + e];
      }
      acc4[ii] += a;
    }
  }
#pragma unroll
  for (int ii = 0; ii < 4; ++ii) {
    int i = tid + ii * 512;
    int tq = i >> 7, e = i & 127;
    outw[(((size_t)(t0 + tq) * Bn + b) * 2048) + c * 512 + e] = acc4[ii];
  }
}

// ---------------------------------------------------------------------------
// Kernel 4: pointer logits + log_softmax (UNCHANGED from R19).
// ---------------------------------------------------------------------------
__global__ __launch_bounds__(512) void pointer_kernel(
    const float* __restrict__ K2,        // [B,N,D] f32 ws
    const int* __restrict__ mask,        // int32 bools
    float* __restrict__ outw) {          // [T,B,2048] f32 (+q2 scratch)
  int t0 = blockIdx.x * TT;
  int b = blockIdx.y;
  int tid = threadIdx.x;
  __shared__ __align__(16) float q2t[TT * Cc * Dd];  // 16 KB
  __shared__ __align__(16) float lg[TT * Cc * Nn];   // 64 KB

  for (int i = tid; i < TT * Cc * Dd; i += 512) {
    int tt = i >> 9, rest = i & 511;
    int c = rest >> 7, d = rest & 127;
    q2t[i] = outw[((size_t)(t0 + tt) * Bn + b) * 2048 + c * 512 + d];
  }
  __syncthreads();

  int n = tid;
  const float* k2p = &K2[((size_t)b * Nn + n) * Dd];
  float acc[TT * Cc];
#pragma unroll
  for (int i = 0; i < TT * Cc; ++i) acc[i] = 0.f;
  for (int dc = 0; dc < 4; ++dc) {
    float4 k4[8];
#pragma unroll
    for (int j = 0; j < 8; ++j) k4[j] = *(const float4*)&k2p[dc * 32 + j * 4];
#pragma unroll
    for (int tc = 0; tc < TT * Cc; ++tc) {
      const float4* q4 = (const float4*)&q2t[tc * Dd + dc * 32];
      float s = 0.f;
#pragma unroll
      for (int j = 0; j < 8; ++j) {
        float4 q = q4[j];
        s += k4[j].x * q.x + k4[j].y * q.y + k4[j].z * q.z + k4[j].w * q.w;
      }
      acc[tc] += s;
    }
  }
  const float rsqD = 0.08838834764831845f;  // 1/sqrt(128)
  for (int tc = 0; tc < TT * Cc; ++tc) {
    int tt = tc >> 2, c = tc & 3;
    float lgt = 10.0f * tanhf(acc[tc] * rsqD);
    int mv = mask[(size_t)(t0 + tt) * (Bn * Cc * Nn) +
                  ((size_t)b * Cc + c) * Nn + n];
    lg[tt * 2048 + c * Nn + n] = mv ? NEGV : lgt;
  }
  __syncthreads();

  int w = tid >> 6, lane = tid & 63;
  float* rowp = &lg[w * 2048];
  float v[32];
  float lmax = -3.0e38f;
#pragma unroll
  for (int k = 0; k < 32; ++k) {
    v[k] = rowp[lane + 64 * k];
    lmax = fmaxf(lmax, v[k]);
  }
#pragma unroll
  for (int off = 32; off; off >>= 1)
    lmax = fmaxf(lmax, __shfl_xor(lmax, off, 64));
  float lsum = 0.f;
#pragma unroll
  for (int k = 0; k < 32; ++k) lsum += __expf(v[k] - lmax);
#pragma unroll
  for (int off = 32; off; off >>= 1) lsum += __shfl_xor(lsum, off, 64);
  float sub = lmax + logf(lsum);
  float* op = &outw[((size_t)(t0 + w) * Bn + b) * 2048];
#pragma unroll
  for (int k = 0; k < 32; ++k) op[lane + 64 * k] = v[k] - sub;
}

// ---------------------------------------------------------------------------
extern "C" void kernel_launch(void* const* d_in, const int* in_sizes, int n_in,
                              void* d_out, int out_size, void* d_ws,
                              size_t ws_size, hipStream_t stream) {
  const float* node = (const float*)d_in[0];
  const float* graph = (const float*)d_in[1];
  const float* sc = (const float*)d_in[2];
  const int* mask = (const int*)d_in[3];
  const float* Wk1 = (const float*)d_in[4];
  const float* Wv = (const float*)d_in[5];
  const float* Wk2 = (const float*)d_in[6];
  const float* Wqf = (const float*)d_in[7];
  const float* Wout = (const float*)d_in[8];
  const float* Wqs = (const float*)d_in[9];
  float* out = (float*)d_out;

  // ws: Qf f32 @0 | K1b bf16 @1MiB (16MiB) | V f32 @18MiB (32MiB)
  //     | K2 f32 @50MiB (32MiB)  -> ends 82 MiB (≤ proven 113 MiB)
  char* ws = (char*)d_ws;
  float* Qf = (float*)(ws);
  u16* K1b = (u16*)(ws + (1u << 20));
  float* V = (float*)(ws + (18u << 20));
  float* K2 = (float*)(ws + (50u << 20));

  hipLaunchKernelGGL(qfixed_kernel, dim3(Bn), dim3(128), 0, stream,
                     graph, Wqf, Qf);
  hipLaunchKernelGGL(proj3_kernel, dim3((Bn * Nn) / PROWS), dim3(128), 0,
                     stream, node, Wk1, Wv, Wk2, K1b, V, K2);
  hipLaunchKernelGGL(mha_kernel, dim3(Tt / TQ, Cc, Bn), dim3(512), 0, stream,
                     Qf, sc, mask, K1b, V, Wqs, Wout, out);
  hipLaunchKernelGGL(pointer_kernel, dim3(Tt / TT, Bn), dim3(512), 0, stream,
                     K2, mask, out);
}

// Round 21
// 636.626 us; speedup vs baseline: 15.3165x; 2.5131x over previous
//
#include <hip/hip_runtime.h>
#include <cstddef>

#define Bn 128   // batch
#define Nn 512   // n_node
#define Cc 4     // n_car
#define Tt 128   // decode steps
#define Dd 128   // model dim
#define Hh 8     // heads
#define NEGV -1e9f

#define TQ 16    // t-tile in MHA kernel
#define TT 8     // t-tile in pointer kernel

typedef unsigned short u16;
typedef unsigned int u32;
typedef __attribute__((ext_vector_type(8))) short bf16x8;
typedef __attribute__((ext_vector_type(4))) float f32x4;

__device__ __forceinline__ u16 f2b(float f) {
  union { float f; u32 i; } x; x.f = f;
  u32 i = x.i; i += 0x7fffu + ((i >> 16) & 1u);
  return (u16)(i >> 16);
}
__device__ __forceinline__ float b2f(u16 u) {
  union { u32 i; float f; } x; x.i = (u32)u << 16; return x.f;
}
__device__ __forceinline__ float fast_tanh(float x) {
  x = fminf(fmaxf(x, -20.f), 20.f);
  float t = __expf(2.f * x);
  return (t - 1.f) / (t + 1.f);
}

// ---------------------------------------------------------------------------
// Kernel 1: Qf = graph @ Wq_fixed  [B,D] f32 -> ws.
// ---------------------------------------------------------------------------
__global__ __launch_bounds__(128) void qfixed_kernel(
    const float* __restrict__ g, const float* __restrict__ Wq,
    float* __restrict__ Qf) {
  int b = blockIdx.x, d = threadIdx.x;
  __shared__ float row[Dd];
  row[d] = g[b * Dd + d];
  __syncthreads();
  float acc = 0.f;
  for (int e = 0; e < Dd; ++e) acc += row[e] * Wq[e * Dd + d];
  Qf[b * Dd + d] = acc;
}

// ---------------------------------------------------------------------------
// Kernel 2: M = Wk2 @ Wout^T  (128x128 f32 -> ws). One block per row f.
// ---------------------------------------------------------------------------
__global__ __launch_bounds__(128) void wmix_kernel(
    const float* __restrict__ Wk2, const float* __restrict__ Wout,
    float* __restrict__ M) {
  int f = blockIdx.x, d = threadIdx.x;
  __shared__ float row[Dd];
  row[d] = Wk2[f * Dd + d];
  __syncthreads();
  float acc = 0.f;
  for (int e = 0; e < Dd; ++e) acc += row[e] * Wout[d * Dd + e];
  M[f * Dd + d] = acc;
}

// ---------------------------------------------------------------------------
// Kernel 3: Q1b = bf16(Qf[b] + sc @ Wqs)  [T*B*C, 128]. 32 rows/block.
// ---------------------------------------------------------------------------
#define QROWS 32
__global__ __launch_bounds__(128) void qstep_kernel(
    const float* __restrict__ Qf, const float* __restrict__ sc,
    const float* __restrict__ Wqs, u16* __restrict__ Q1b) {
  int r0 = blockIdx.x * QROWS, d = threadIdx.x;
  __shared__ float rows[QROWS * 129];
  for (int i = d; i < QROWS * 129; i += 128)
    rows[i] = sc[(size_t)r0 * 129 + i];
  __syncthreads();
  float acc[QROWS];
#pragma unroll
  for (int r = 0; r < QROWS; ++r) {
    int b = ((r0 + r) >> 2) & 127;
    acc[r] = Qf[b * Dd + d];
  }
  for (int e = 0; e < 129; ++e) {
    float w = Wqs[e * Dd + d];
#pragma unroll
    for (int r = 0; r < QROWS; ++r) acc[r] += rows[r * 129 + e] * w;
  }
  for (int r = 0; r < QROWS; ++r)
    Q1b[(size_t)(r0 + r) * Dd + d] = f2b(acc[r]);
}

// ---------------------------------------------------------------------------
// Kernel 4: K1b/Vb/K2p (all bf16) = node @ {Wk1, Wv, M}. 32 rows/block.
// ---------------------------------------------------------------------------
#define PROWS 32
__global__ __launch_bounds__(128) void proj3_kernel(
    const float* __restrict__ X,
    const float* __restrict__ W1, const float* __restrict__ W2,
    const float* __restrict__ W3,
    u16* __restrict__ O1, u16* __restrict__ O2, u16* __restrict__ O3) {
  int r0 = blockIdx.x * PROWS, d = threadIdx.x;
  __shared__ __align__(16) float rows[PROWS][Dd];
  for (int r = 0; r < PROWS; ++r)
    rows[r][d] = X[(size_t)(r0 + r) * Dd + d];
  __syncthreads();

  const float* Ws[3] = {W1, W2, W3};
  u16* Os[3] = {O1, O2, O3};
  for (int m = 0; m < 3; ++m) {
    const float* __restrict__ W = Ws[m];
    float acc[PROWS];
#pragma unroll
    for (int r = 0; r < PROWS; ++r) acc[r] = 0.f;
    for (int e4 = 0; e4 < Dd / 4; ++e4) {
      float w0 = W[(e4 * 4 + 0) * Dd + d];
      float w1 = W[(e4 * 4 + 1) * Dd + d];
      float w2 = W[(e4 * 4 + 2) * Dd + d];
      float w3 = W[(e4 * 4 + 3) * Dd + d];
#pragma unroll
      for (int r = 0; r < PROWS; ++r) {
        float4 x = *(const float4*)&rows[r][e4 * 4];
        acc[r] += x.x * w0 + x.y * w1 + x.z * w2 + x.w * w3;
      }
    }
    u16* __restrict__ O = Os[m];
    for (int r = 0; r < PROWS; ++r) O[(size_t)(r0 + r) * Dd + d] = f2b(acc[r]);
  }
}

// ---------------------------------------------------------------------------
// Kernel 5: lean MFMA MHA. grid (T/TQ, C, B), 512 thr. Writes o -> out
// scratch slots out[t,b, c*512+0..127]. LDS 50 KB -> 3 blocks/CU.
// ---------------------------------------------------------------------------
__global__ __launch_bounds__(512) void mha_kernel(
    const u16* __restrict__ Q1b,         // [T*B*C,128] bf16 ws
    const int* __restrict__ mask,        // [T,B,C,N] int32
    const u16* __restrict__ K1b,         // [B,N,D] bf16 ws
    const u16* __restrict__ Vb,          // [B,N,D] bf16 ws
    float* __restrict__ outw) {          // d_out: o scratch
  const int t0 = blockIdx.x * TQ;
  const int c = blockIdx.y;
  const int b = blockIdx.z;
  const int tid = threadIdx.x;
  const int w = tid >> 6, lane = tid & 63;
  const int l15 = lane & 15, g = lane >> 4;

  __shared__ u16 scoresPb[TQ * 520];     // bf16 scores, then P (same slots)
  __shared__ u16 Vt[16 * 520];           // V-head transposed bf16
  __shared__ __align__(16) float otp[8 * 272];  // PV partials [w][16][17]
  __shared__ __align__(16) float otile[TQ * 128];
  __shared__ u32 mkbits[16 * 16];

  // ---- mask bitset
  {
    int n = tid;
    u32 mbits = 0;
    for (int tq = 0; tq < TQ; ++tq) {
      int mv = mask[(size_t)(t0 + tq) * (Bn * Cc * Nn) +
                    ((size_t)b * Cc + c) * Nn + n];
      mbits |= ((u32)(mv != 0)) << tq;
    }
    for (int tq = 0; tq < TQ; ++tq) {
      unsigned long long bal = __ballot((mbits >> tq) & 1u);
      if (lane == 0) {
        mkbits[tq * 16 + 2 * w] = (u32)bal;
        mkbits[tq * 16 + 2 * w + 1] = (u32)(bal >> 32);
      }
    }
  }
  __syncthreads();

  for (int h = 0; h < Hh; ++h) {
    // (a) stage Vt (bf16 transposed) + scores MFMA
    for (int i = tid; i < 1024; i += 512) {
      int n = i >> 1, jj = i & 1;
      uint4 v = *(const uint4*)&Vb[((size_t)b * Nn + n) * Dd + h * 16 + jj * 8];
      u32 dws[4] = {v.x, v.y, v.z, v.w};
#pragma unroll
      for (int m = 0; m < 4; ++m) {
        Vt[(jj * 8 + m * 2 + 0) * 520 + n] = (u16)(dws[m] & 0xffffu);
        Vt[(jj * 8 + m * 2 + 1) * 520 + n] = (u16)(dws[m] >> 16);
      }
    }
    {
      // A-frag: Q1 row t0+l15, k = g*8+j (zero for k>=16)
      bf16x8 a8 = (bf16x8)(short)0;
      if (g < 2) {
        union { uint4 u; bf16x8 s; } cv;
        cv.u = *(const uint4*)&Q1b[((((size_t)(t0 + l15) * Bn) + b) * Cc + c) *
                                       Dd + h * 16 + g * 8];
        a8 = cv.s;
      }
      for (int nt = w * 4; nt < w * 4 + 4; ++nt) {
        int n0 = nt * 16;
        bf16x8 b8 = (bf16x8)(short)0;
        if (g < 2) {
          union { uint4 u; bf16x8 s; } cv;
          cv.u = *(const uint4*)&K1b[((size_t)b * Nn + n0 + l15) * Dd + h * 16 +
                                     g * 8];
          b8 = cv.s;
        }
        f32x4 cc = {0.f, 0.f, 0.f, 0.f};
        cc = __builtin_amdgcn_mfma_f32_16x16x32_bf16(a8, b8, cc, 0, 0, 0);
#pragma unroll
        for (int r = 0; r < 4; ++r)
          scoresPb[(g * 4 + r) * 520 + n0 + l15] = f2b(cc[r]);
      }
    }
    __syncthreads();

    // (b) softmax: wave w rows {2w,2w+1}; read scores, write P to SAME slots
#pragma unroll
    for (int r = 0; r < 2; ++r) {
      int tq = 2 * w + r;
      float pv[8];
      float mx = -3.0e38f;
#pragma unroll
      for (int k = 0; k < 8; ++k) {
        int n = lane + 64 * k;
        float s = b2f(scoresPb[tq * 520 + n]);
        u32 bit = (mkbits[tq * 16 + (n >> 5)] >> (n & 31)) & 1u;
        s = bit ? NEGV : 0.25f * s;
        pv[k] = s;
        mx = fmaxf(mx, s);
      }
#pragma unroll
      for (int off = 32; off; off >>= 1)
        mx = fmaxf(mx, __shfl_xor(mx, off, 64));
      float sum = 0.f;
#pragma unroll
      for (int k = 0; k < 8; ++k) {
        float e = __expf(pv[k] - mx);
        pv[k] = e;
        sum += e;
      }
#pragma unroll
      for (int off = 32; off; off >>= 1) sum += __shfl_xor(sum, off, 64);
      float inv = 1.0f / sum;
#pragma unroll
      for (int k = 0; k < 8; ++k)
        scoresPb[tq * 520 + lane + 64 * k] = f2b(pv[k] * inv);
    }
    __syncthreads();

    // (c) PV: wave w covers k in [64w,64w+64): 2 mfma K=32
    {
      f32x4 cc = {0.f, 0.f, 0.f, 0.f};
#pragma unroll
      for (int kk = 0; kk < 2; ++kk) {
        int k0 = w * 64 + kk * 32;
        union { uint4 u; bf16x8 s; } pa, vb;
        pa.u = *(const uint4*)&scoresPb[l15 * 520 + k0 + g * 8];
        vb.u = *(const uint4*)&Vt[l15 * 520 + k0 + g * 8];
        cc = __builtin_amdgcn_mfma_f32_16x16x32_bf16(pa.s, vb.s, cc, 0, 0, 0);
      }
#pragma unroll
      for (int r = 0; r < 4; ++r)
        otp[w * 272 + (g * 4 + r) * 17 + l15] = cc[r];
    }
    __syncthreads();

    // (d) reduce partials -> otile[:, h*16..]
    if (tid < 256) {
      int tq = tid >> 4, d = tid & 15;
      float s = 0.f;
#pragma unroll
      for (int w2 = 0; w2 < 8; ++w2) s += otp[w2 * 272 + tq * 17 + d];
      otile[tq * 128 + h * 16 + d] = s;
    }
    __syncthreads();
  }

  // ---- write o (f32) to out scratch
  for (int i = tid; i < TQ * 128; i += 512) {
    int tq = i >> 7, e = i & 127;
    outw[(((size_t)(t0 + tq) * Bn + b) * 2048) + c * 512 + e] = otile[i];
  }
}

// ---------------------------------------------------------------------------
// Kernel 6: MFMA pointer: logits = o @ K2p^T, tanh-clip, mask, LSE -> out.
// grid (T/TT, B), 512 thr. LDS ~43.5 KB -> 3 blocks/CU.
// ---------------------------------------------------------------------------
__global__ __launch_bounds__(512) void pointer_kernel(
    const u16* __restrict__ K2p,         // [B,N,D] bf16 ws
    const int* __restrict__ mask,        // int32 bools
    float* __restrict__ outw) {          // [T,B,2048] f32 (+o scratch)
  const int t0 = blockIdx.x * TT;
  const int b = blockIdx.y;
  const int tid = threadIdx.x;
  const int w = tid >> 6, lane = tid & 63;
  const int l15 = lane & 15, g = lane >> 4;

  __shared__ u16 otb[32 * 136];          // o rows (tt*4+c) bf16
  __shared__ u16 lgb[TT * 2048];         // logits bf16
  __shared__ u32 mkb[32 * 16];

  // stage o -> bf16 (read scratch BEFORE overwriting), + mask bits
  for (int i = tid; i < 4096; i += 512) {
    int row = i >> 7, d = i & 127;
    int tt = row >> 2, c = row & 3;
    otb[row * 136 + d] =
        f2b(outw[((size_t)(t0 + tt) * Bn + b) * 2048 + c * 512 + d]);
  }
  {
    int n = tid;
    for (int tc = 0; tc < 32; ++tc) {
      int tt = tc >> 2, c = tc & 3;
      int mv = mask[(size_t)(t0 + tt) * (Bn * Cc * Nn) +
                    ((size_t)b * Cc + c) * Nn + n];
      unsigned long long bal = __ballot(mv != 0);
      if (lane == 0) {
        mkb[tc * 16 + 2 * w] = (u32)bal;
        mkb[tc * 16 + 2 * w + 1] = (u32)(bal >> 32);
      }
    }
  }
  __syncthreads();

  // MFMA: wave w -> mt = w>>2, nt in [(w&3)*8, +8)
  const float rsqD = 0.08838834764831845f;  // 1/sqrt(128)
  {
    const int mt = w >> 2;
    const int nt0 = (w & 3) * 8;
    bf16x8 a8[4];
#pragma unroll
    for (int dc = 0; dc < 4; ++dc) {
      union { uint4 u; bf16x8 s; } cv;
      cv.u = *(const uint4*)&otb[(mt * 16 + l15) * 136 + dc * 32 + g * 8];
      a8[dc] = cv.s;
    }
    for (int nt = nt0; nt < nt0 + 8; ++nt) {
      int n0 = nt * 16;
      f32x4 cc = {0.f, 0.f, 0.f, 0.f};
#pragma unroll
      for (int dc = 0; dc < 4; ++dc) {
        union { uint4 u; bf16x8 s; } cv;
        cv.u = *(const uint4*)&K2p[((size_t)b * Nn + n0 + l15) * Dd + dc * 32 +
                                   g * 8];
        cc = __builtin_amdgcn_mfma_f32_16x16x32_bf16(a8[dc], cv.s, cc, 0, 0, 0);
      }
      int n = n0 + l15;
#pragma unroll
      for (int r = 0; r < 4; ++r) {
        int row = mt * 16 + g * 4 + r;  // = tt*4 + c
        int tt = row >> 2, c = row & 3;
        u32 bit = (mkb[row * 16 + (n >> 5)] >> (n & 31)) & 1u;
        float lgt = 10.0f * fast_tanh(cc[r] * rsqD);
        lgb[tt * 2048 + c * 512 + n] = f2b(bit ? NEGV : lgt);
      }
    }
  }
  __syncthreads();

  // log_softmax per tt row (2048 wide); wave w handles row tt=w
  float v[32];
  float lmax = -3.0e38f;
#pragma unroll
  for (int k = 0; k < 32; ++k) {
    v[k] = b2f(lgb[w * 2048 + lane + 64 * k]);
    lmax = fmaxf(lmax, v[k]);
  }
#pragma unroll
  for (int off = 32; off; off >>= 1)
    lmax = fmaxf(lmax, __shfl_xor(lmax, off, 64));
  float lsum = 0.f;
#pragma unroll
  for (int k = 0; k < 32; ++k) lsum += __expf(v[k] - lmax);
#pragma unroll
  for (int off = 32; off; off >>= 1) lsum += __shfl_xor(lsum, off, 64);
  float sub = lmax + logf(lsum);
  float* op = &outw[((size_t)(t0 + w) * Bn + b) * 2048];
#pragma unroll
  for (int k = 0; k < 32; ++k) op[lane + 64 * k] = v[k] - sub;
}

// ---------------------------------------------------------------------------
extern "C" void kernel_launch(void* const* d_in, const int* in_sizes, int n_in,
                              void* d_out, int out_size, void* d_ws,
                              size_t ws_size, hipStream_t stream) {
  const float* node = (const float*)d_in[0];
  const float* graph = (const float*)d_in[1];
  const float* sc = (const float*)d_in[2];
  const int* mask = (const int*)d_in[3];
  const float* Wk1 = (const float*)d_in[4];
  const float* Wv = (const float*)d_in[5];
  const float* Wk2 = (const float*)d_in[6];
  const float* Wqf = (const float*)d_in[7];
  const float* Wout = (const float*)d_in[8];
  const float* Wqs = (const float*)d_in[9];
  float* out = (float*)d_out;

  // ws: Qf f32 @0 | M f32 @128KiB | Q1b bf16 @1MiB (4MiB) | K1b @6MiB (16MiB)
  //     | Vb @22MiB (16MiB) | K2p @38MiB (16MiB) -> ends 54MiB (proven safe)
  char* ws = (char*)d_ws;
  float* Qf = (float*)(ws);
  float* M = (float*)(ws + (128u << 10));
  u16* Q1b = (u16*)(ws + (1u << 20));
  u16* K1b = (u16*)(ws + (6u << 20));
  u16* Vb = (u16*)(ws + (22u << 20));
  u16* K2p = (u16*)(ws + (38u << 20));

  hipLaunchKernelGGL(qfixed_kernel, dim3(Bn), dim3(128), 0, stream,
                     graph, Wqf, Qf);
  hipLaunchKernelGGL(wmix_kernel, dim3(128), dim3(128), 0, stream,
                     Wk2, Wout, M);
  hipLaunchKernelGGL(qstep_kernel, dim3((Tt * Bn * Cc) / QROWS), dim3(128), 0,
                     stream, Qf, sc, Wqs, Q1b);
  hipLaunchKernelGGL(proj3_kernel, dim3((Bn * Nn) / PROWS), dim3(128), 0,
                     stream, node, Wk1, Wv, M, K1b, Vb, K2p);
  hipLaunchKernelGGL(mha_kernel, dim3(Tt / TQ, Cc, Bn), dim3(512), 0, stream,
                     Q1b, mask, K1b, Vb, out);
  hipLaunchKernelGGL(pointer_kernel, dim3(Tt / TT, Bn), dim3(512), 0, stream,
                     K2p, mask, out);
}